// Round 5
// baseline (74.476 us; speedup 1.0000x reference)
//
#include <hip/hip_runtime.h>
#include <hip/hip_bf16.h>
#include <math.h>

#define NS 512
#define OD 128
#define BB 64
#define TT 2000
#define KK 400
#define CHUNK 128
#define NCH 16
#define LOG2PI_F 1.8378770664093453f
#define SEQ_OFF  576     // ws float offset: per-batch seq partials [BB]
#define CNT_OFF  640     // ws int offset: per-batch arrival counters [BB]
#define PART_OFF 1024    // ws float offset: obs partials [BB*NCH]

// ws layout (floats):
//   [0,512) row_lse   [512] init_lse
//   [SEQ_OFF,+64)  duration + trans-numerator + init_logit partial per batch
//   [CNT_OFF,+64)  (int) arrival counters, zeroed by K1 each launch
//   [PART_OFF,+1024) obs partials (already scaled by -0.5)

__device__ __forceinline__ float softplusf(float x) {
    return (x > 20.f) ? x : log1pf(expf(x));
}

// K1: 513 LSE blocks + 64 seq blocks. No intra-kernel dependencies.
__global__ __launch_bounds__(256) void k1_kernel(
    const float* __restrict__ trans, const float* __restrict__ init_logits,
    const float* __restrict__ alpha_p, const float* __restrict__ beta_p,
    const int* __restrict__ states, const int* __restrict__ durs,
    float* __restrict__ ws)
{
    const int tid = threadIdx.x;
    const int bid = blockIdx.x;
    __shared__ float red[4];

    if (bid <= NS) {
        // LSE of transition row bid, or of initial logits (bid==512)
        const float* src = (bid < NS) ? (trans + (size_t)bid * NS) : init_logits;
        float x0 = src[tid];
        float x1 = src[tid + 256];
        float m = fmaxf(x0, x1);
        for (int off = 32; off; off >>= 1) m = fmaxf(m, __shfl_down(m, off, 64));
        if ((tid & 63) == 0) red[tid >> 6] = m;
        __syncthreads();
        m = fmaxf(fmaxf(red[0], red[1]), fmaxf(red[2], red[3]));
        __syncthreads();
        float e = __expf(x0 - m) + __expf(x1 - m);
        for (int off = 32; off; off >>= 1) e += __shfl_down(e, off, 64);
        if ((tid & 63) == 0) red[tid >> 6] = e;
        __syncthreads();
        if (tid == 0)
            ws[(bid < NS) ? bid : 512] = m + __logf(red[0] + red[1] + red[2] + red[3]);
    } else {
        // seq partial for batch b: duration terms + transition numerators + init logit
        const int b = bid - (NS + 1);
        if (tid == 0) ((int*)ws)[CNT_OFF + b] = 0;   // clean counter for K2
        float lp = 0.f;
        for (int k = tid; k < KK; k += 256) {
            const int s = states[b * KK + k];
            const float dv = (float)durs[b * KK + k];
            const float a  = softplusf(alpha_p[s]) + 1e-6f;
            const float bt = softplusf(beta_p[s]) + 1e-6f;
            float v = (a - 1.f) * __logf(dv + 1e-8f) - bt * dv
                    + a * __logf(bt) - lgammaf(a);
            lp += (dv >= 1.f) ? v : -INFINITY;
            if (k < KK - 1)
                lp += trans[(size_t)s * NS + states[b * KK + k + 1]];
        }
        for (int off = 32; off; off >>= 1) lp += __shfl_down(lp, off, 64);
        if ((tid & 63) == 0) red[tid >> 6] = lp;
        __syncthreads();
        if (tid == 0)
            ws[SEQ_OFF + b] = red[0] + red[1] + red[2] + red[3]
                            + init_logits[states[b * KK]];
    }
}

// K2: 1024 obs blocks; last arriver per batch finishes out[b]. No spinning.
__global__ __launch_bounds__(256) void k2_kernel(
    const float* __restrict__ obs, const float* __restrict__ mu,
    const float* __restrict__ lvar,
    const int* __restrict__ states, const int* __restrict__ durs,
    float* __restrict__ ws, float* __restrict__ out)
{
    const int tid = threadIdx.x;
    const int bid = blockIdx.x;
    const int b = bid >> 4;
    const int t0 = (bid & 15) * CHUNK;

    __shared__ float red[4];
    __shared__ int st[KK];
    __shared__ int cum[512];
    __shared__ int csum[8];
    __shared__ int fsl[CHUNK];
    __shared__ int sh_last;

    // load states + durations; wave-shuffle inclusive scan of durations
    const int lane = tid & 63, w = tid >> 6;
    int v0 = 0, v1 = 0;
    if (tid < KK) { st[tid] = states[b * KK + tid]; v0 = durs[b * KK + tid]; }
    if (tid + 256 < KK) { st[tid + 256] = states[b * KK + tid + 256];
                          v1 = durs[b * KK + tid + 256]; }
    #pragma unroll
    for (int off = 1; off < 64; off <<= 1) {
        int u0 = __shfl_up(v0, off, 64);
        int u1 = __shfl_up(v1, off, 64);
        if (lane >= off) { v0 += u0; v1 += u1; }
    }
    if (lane == 63) { csum[w] = v0; csum[4 + w] = v1; }
    __syncthreads();
    int off0 = 0, off1 = 0;
    #pragma unroll
    for (int c = 0; c < 8; ++c) {
        int cs = csum[c];
        off0 += (c < w) ? cs : 0;
        off1 += (c < 4 + w) ? cs : 0;
    }
    cum[tid] = v0 + off0;
    cum[tid + 256] = v1 + off1;
    __syncthreads();

    // frame->state for this chunk (searchsorted side='right', clip to K-1)
    if (tid < CHUNK) {
        const int t = t0 + tid;
        int lo = 0, hi = KK;
        while (lo < hi) {
            int mid = (lo + hi) >> 1;
            if (cum[mid] <= t) lo = mid + 1; else hi = mid;
        }
        fsl[tid] = st[(lo > KK - 1) ? (KK - 1) : lo];
    }
    __syncthreads();

    const int row = tid >> 5;
    const int d = (tid & 31) * 4;
    float acc = 0.f;
    if (t0 + CHUNK <= TT) {
        #pragma unroll
        for (int i = 0; i < CHUNK / 8; ++i) {
            const int t = t0 + i * 8 + row;
            const int s = fsl[i * 8 + row];
            const float4 o  = *(const float4*)(obs + ((size_t)(b * TT + t)) * OD + d);
            const float4 m  = *(const float4*)(mu  + (size_t)s * OD + d);
            const float4 lv = *(const float4*)(lvar + (size_t)s * OD + d);
            const float dx = o.x - m.x, dy = o.y - m.y, dz = o.z - m.z, dw = o.w - m.w;
            acc += lv.x + lv.y + lv.z + lv.w + 4.f * LOG2PI_F
                 + dx * dx * __expf(-lv.x) + dy * dy * __expf(-lv.y)
                 + dz * dz * __expf(-lv.z) + dw * dw * __expf(-lv.w);
        }
    } else {
        #pragma unroll
        for (int i = 0; i < CHUNK / 8; ++i) {
            const int t = t0 + i * 8 + row;
            if (t < TT) {
                const int s = fsl[i * 8 + row];
                const float4 o  = *(const float4*)(obs + ((size_t)(b * TT + t)) * OD + d);
                const float4 m  = *(const float4*)(mu  + (size_t)s * OD + d);
                const float4 lv = *(const float4*)(lvar + (size_t)s * OD + d);
                const float dx = o.x - m.x, dy = o.y - m.y, dz = o.z - m.z, dw = o.w - m.w;
                acc += lv.x + lv.y + lv.z + lv.w + 4.f * LOG2PI_F
                     + dx * dx * __expf(-lv.x) + dy * dy * __expf(-lv.y)
                     + dz * dz * __expf(-lv.z) + dw * dw * __expf(-lv.w);
            }
        }
    }
    for (int off = 32; off; off >>= 1) acc += __shfl_down(acc, off, 64);
    if ((tid & 63) == 0) red[tid >> 6] = acc;
    __syncthreads();
    if (tid == 0) {
        ws[PART_OFF + bid] = -0.5f * (red[0] + red[1] + red[2] + red[3]);
        __threadfence();
        int old = atomicAdd(&((int*)ws)[CNT_OFF + b], 1);
        sh_last = (old == NCH - 1);
    }
    __syncthreads();

    if (sh_last) {
        __threadfence();   // acquire: make sibling partials visible
        float lp = 0.f;
        if (tid < NCH)       lp = ws[PART_OFF + b * NCH + tid];
        else if (tid == NCH) lp = ws[SEQ_OFF + b] - ws[512];
        for (int k = tid; k < KK - 1; k += 256)
            lp -= ws[st[k]];                    // row_lse per transition, L1-hot
        for (int off = 32; off; off >>= 1) lp += __shfl_down(lp, off, 64);
        if ((tid & 63) == 0) red[tid >> 6] = lp;
        __syncthreads();
        if (tid == 0)
            out[b] = red[0] + red[1] + red[2] + red[3];
    }
}

extern "C" void kernel_launch(void* const* d_in, const int* in_sizes, int n_in,
                              void* d_out, int out_size, void* d_ws, size_t ws_size,
                              hipStream_t stream) {
    const float* observations = (const float*)d_in[0];
    const float* alpha_p      = (const float*)d_in[1];
    const float* beta_p       = (const float*)d_in[2];
    const float* trans        = (const float*)d_in[3];
    const float* init_logits  = (const float*)d_in[4];
    const float* obs_means    = (const float*)d_in[5];
    const float* obs_logvars  = (const float*)d_in[6];
    const int*   state_seq    = (const int*)d_in[7];
    const int*   dur_seq      = (const int*)d_in[8];

    float* ws = (float*)d_ws;
    float* out = (float*)d_out;

    k1_kernel<<<NS + 1 + BB, 256, 0, stream>>>(
        trans, init_logits, alpha_p, beta_p, state_seq, dur_seq, ws);
    k2_kernel<<<BB * NCH, 256, 0, stream>>>(
        observations, obs_means, obs_logvars, state_seq, dur_seq, ws, out);
}

// Round 6
// 24.304 us; speedup vs baseline: 3.0643x; 3.0643x over previous
//
#include <hip/hip_runtime.h>
#include <hip/hip_bf16.h>
#include <math.h>

#define NS 512
#define OD 128
#define BB 64
#define TT 2000
#define KK 400
#define CHUNK 64
#define NCH 32            // chunks per batch: 2000/64 -> 32 (last partial)
#define LOG2PI_F 1.8378770664093453f
#define SEQ_OFF  576      // ws float offset: per-batch seq partials [BB]
#define PART_OFF 1024     // ws float offset: obs partials [BB*NCH]

// ws layout (floats):
//   [0,512) row_lse   [512] init_lse
//   [SEQ_OFF,+64)   duration + trans-numerator + init_logit partial per batch
//   [PART_OFF,+2048) obs partials (scaled by -0.5)

__device__ __forceinline__ float softplusf(float x) {
    return (x > 20.f) ? x : log1pf(expf(x));
}

// grid: [0, BB*NCH) obs | [BB*NCH, +NS+1) lse | [+BB) seq. No cross-block deps.
__global__ __launch_bounds__(256) void big_kernel(
    const float* __restrict__ obs, const float* __restrict__ mu,
    const float* __restrict__ lvar, const float* __restrict__ trans,
    const float* __restrict__ init_logits,
    const float* __restrict__ alpha_p, const float* __restrict__ beta_p,
    const int* __restrict__ states, const int* __restrict__ durs,
    float* __restrict__ ws)
{
    const int tid = threadIdx.x;
    const int bid = blockIdx.x;
    __shared__ float red[4];

    if (bid < BB * NCH) {
        // ---- observation partial for (batch b, 64-frame chunk) ----
        const int b = bid >> 5;
        const int t0 = (bid & 31) * CHUNK;

        __shared__ int st[KK];
        __shared__ int cum[512];
        __shared__ int csum[8];
        __shared__ int fsl[CHUNK];

        // load states + durations; wave-shuffle inclusive scan of durations
        const int lane = tid & 63, w = tid >> 6;
        int v0 = 0, v1 = 0;
        if (tid < KK) { st[tid] = states[b * KK + tid]; v0 = durs[b * KK + tid]; }
        if (tid + 256 < KK) { st[tid + 256] = states[b * KK + tid + 256];
                              v1 = durs[b * KK + tid + 256]; }
        #pragma unroll
        for (int off = 1; off < 64; off <<= 1) {
            int u0 = __shfl_up(v0, off, 64);
            int u1 = __shfl_up(v1, off, 64);
            if (lane >= off) { v0 += u0; v1 += u1; }
        }
        if (lane == 63) { csum[w] = v0; csum[4 + w] = v1; }
        __syncthreads();
        int off0 = 0, off1 = 0;
        #pragma unroll
        for (int c = 0; c < 8; ++c) {
            int cs = csum[c];
            off0 += (c < w) ? cs : 0;
            off1 += (c < 4 + w) ? cs : 0;
        }
        cum[tid] = v0 + off0;
        cum[tid + 256] = v1 + off1;
        __syncthreads();

        // frame->state for this chunk (searchsorted side='right', clip to K-1)
        if (tid < CHUNK) {
            const int t = t0 + tid;
            int lo = 0, hi = KK;
            while (lo < hi) {
                int mid = (lo + hi) >> 1;
                if (cum[mid] <= t) lo = mid + 1; else hi = mid;
            }
            fsl[tid] = st[(lo > KK - 1) ? (KK - 1) : lo];
        }
        __syncthreads();

        const int row = tid >> 5;          // 8 frames per iter
        const int d = (tid & 31) * 4;
        float acc = 0.f;
        if (t0 + CHUNK <= TT) {
            #pragma unroll
            for (int i = 0; i < CHUNK / 8; ++i) {
                const int t = t0 + i * 8 + row;
                const int s = fsl[i * 8 + row];
                const float4 o  = *(const float4*)(obs + ((size_t)(b * TT + t)) * OD + d);
                const float4 m  = *(const float4*)(mu  + (size_t)s * OD + d);
                const float4 lv = *(const float4*)(lvar + (size_t)s * OD + d);
                const float dx = o.x - m.x, dy = o.y - m.y, dz = o.z - m.z, dw = o.w - m.w;
                acc += lv.x + lv.y + lv.z + lv.w + 4.f * LOG2PI_F
                     + dx * dx * __expf(-lv.x) + dy * dy * __expf(-lv.y)
                     + dz * dz * __expf(-lv.z) + dw * dw * __expf(-lv.w);
            }
        } else {
            #pragma unroll
            for (int i = 0; i < CHUNK / 8; ++i) {
                const int t = t0 + i * 8 + row;
                if (t < TT) {
                    const int s = fsl[i * 8 + row];
                    const float4 o  = *(const float4*)(obs + ((size_t)(b * TT + t)) * OD + d);
                    const float4 m  = *(const float4*)(mu  + (size_t)s * OD + d);
                    const float4 lv = *(const float4*)(lvar + (size_t)s * OD + d);
                    const float dx = o.x - m.x, dy = o.y - m.y, dz = o.z - m.z, dw = o.w - m.w;
                    acc += lv.x + lv.y + lv.z + lv.w + 4.f * LOG2PI_F
                         + dx * dx * __expf(-lv.x) + dy * dy * __expf(-lv.y)
                         + dz * dz * __expf(-lv.z) + dw * dw * __expf(-lv.w);
                }
            }
        }
        for (int off = 32; off; off >>= 1) acc += __shfl_down(acc, off, 64);
        if ((tid & 63) == 0) red[tid >> 6] = acc;
        __syncthreads();
        if (tid == 0)
            ws[PART_OFF + bid] = -0.5f * (red[0] + red[1] + red[2] + red[3]);
    } else if (bid < BB * NCH + NS + 1) {
        // ---- LSE: transition row r<512, or initial logits (r==512) ----
        const int r = bid - BB * NCH;
        const float* src = (r < NS) ? (trans + (size_t)r * NS) : init_logits;
        float x0 = src[tid];
        float x1 = src[tid + 256];
        float m = fmaxf(x0, x1);
        for (int off = 32; off; off >>= 1) m = fmaxf(m, __shfl_down(m, off, 64));
        if ((tid & 63) == 0) red[tid >> 6] = m;
        __syncthreads();
        m = fmaxf(fmaxf(red[0], red[1]), fmaxf(red[2], red[3]));
        __syncthreads();
        float e = __expf(x0 - m) + __expf(x1 - m);
        for (int off = 32; off; off >>= 1) e += __shfl_down(e, off, 64);
        if ((tid & 63) == 0) red[tid >> 6] = e;
        __syncthreads();
        if (tid == 0)
            ws[(r < NS) ? r : 512] = m + __logf(red[0] + red[1] + red[2] + red[3]);
    } else {
        // ---- seq: duration terms + transition numerators + init logit ----
        const int b = bid - (BB * NCH + NS + 1);
        float lp = 0.f;
        for (int k = tid; k < KK; k += 256) {
            const int s = states[b * KK + k];
            const float dv = (float)durs[b * KK + k];
            const float a  = softplusf(alpha_p[s]) + 1e-6f;
            const float bt = softplusf(beta_p[s]) + 1e-6f;
            float v = (a - 1.f) * __logf(dv + 1e-8f) - bt * dv
                    + a * __logf(bt) - lgammaf(a);
            lp += (dv >= 1.f) ? v : -INFINITY;
            if (k < KK - 1)
                lp += trans[(size_t)s * NS + states[b * KK + k + 1]];
        }
        for (int off = 32; off; off >>= 1) lp += __shfl_down(lp, off, 64);
        if ((tid & 63) == 0) red[tid >> 6] = lp;
        __syncthreads();
        if (tid == 0)
            ws[SEQ_OFF + b] = red[0] + red[1] + red[2] + red[3]
                            + init_logits[states[b * KK]];
    }
}

__global__ __launch_bounds__(256) void fin_kernel(
    const int* __restrict__ states, const float* __restrict__ ws,
    float* __restrict__ out)
{
    const int b = blockIdx.x;
    const int tid = threadIdx.x;
    __shared__ float red[4];

    float lp = 0.f;
    if (tid < NCH)       lp = ws[PART_OFF + b * NCH + tid];
    else if (tid == NCH) lp = ws[SEQ_OFF + b] - ws[512];
    // subtract row_lse for each transition (2 KB table, L1-hot)
    for (int k = tid; k < KK - 1; k += 256)
        lp -= ws[states[b * KK + k]];
    for (int off = 32; off; off >>= 1) lp += __shfl_down(lp, off, 64);
    if ((tid & 63) == 0) red[tid >> 6] = lp;
    __syncthreads();
    if (tid == 0)
        out[b] = red[0] + red[1] + red[2] + red[3];
}

extern "C" void kernel_launch(void* const* d_in, const int* in_sizes, int n_in,
                              void* d_out, int out_size, void* d_ws, size_t ws_size,
                              hipStream_t stream) {
    const float* observations = (const float*)d_in[0];
    const float* alpha_p      = (const float*)d_in[1];
    const float* beta_p       = (const float*)d_in[2];
    const float* trans        = (const float*)d_in[3];
    const float* init_logits  = (const float*)d_in[4];
    const float* obs_means    = (const float*)d_in[5];
    const float* obs_logvars  = (const float*)d_in[6];
    const int*   state_seq    = (const int*)d_in[7];
    const int*   dur_seq      = (const int*)d_in[8];

    float* ws = (float*)d_ws;
    float* out = (float*)d_out;

    big_kernel<<<BB * NCH + NS + 1 + BB, 256, 0, stream>>>(
        observations, obs_means, obs_logvars, trans, init_logits,
        alpha_p, beta_p, state_seq, dur_seq, ws);
    fin_kernel<<<BB, 256, 0, stream>>>(state_seq, ws, out);
}

// Round 7
// 23.265 us; speedup vs baseline: 3.2011x; 1.0447x over previous
//
#include <hip/hip_runtime.h>
#include <hip/hip_bf16.h>
#include <math.h>

#define NS 512
#define OD 128
#define BB 64
#define TT 2000
#define KK 400
#define CHUNK 128
#define NCH 16
#define LOG2PI_F 1.8378770664093453f
#define SEQ_OFF  576      // ws float offset: per-batch seq partials [BB]
#define PART_OFF 1024     // ws float offset: obs partials [BB*NCH]

// ws layout (floats):
//   [0,512) row_lse   [512] init_lse
//   [SEQ_OFF,+64)   duration + trans-numerator + init_logit partial per batch
//   [PART_OFF,+1024) obs partials (scaled by -0.5)

__device__ __forceinline__ float softplusf(float x) {
    return (x > 20.f) ? x : log1pf(expf(x));
}

// grid: [0, BB*NCH) obs | [BB*NCH, +NS+1) lse | [+BB) seq. No cross-block deps.
__global__ __launch_bounds__(256) void big_kernel(
    const float* __restrict__ obs, const float* __restrict__ mu,
    const float* __restrict__ lvar, const float* __restrict__ trans,
    const float* __restrict__ init_logits,
    const float* __restrict__ alpha_p, const float* __restrict__ beta_p,
    const int* __restrict__ states, const int* __restrict__ durs,
    float* __restrict__ ws)
{
    const int tid = threadIdx.x;
    const int bid = blockIdx.x;
    __shared__ float red[4];

    if (bid < BB * NCH) {
        // ---- observation partial for (batch b, 128-frame chunk) ----
        const int b = bid >> 4;
        const int t0 = (bid & 15) * CHUNK;

        __shared__ int fsl[CHUNK];
        __shared__ int csum[8];

        // states+durations -> registers; wave-shuffle inclusive scan of durs
        const int lane = tid & 63, w = tid >> 6;
        int s0v = 0, d0 = 0, s1v = 0, d1 = 0;
        s0v = states[b * KK + tid];                 // tid < 400 always
        d0  = durs[b * KK + tid];
        if (tid + 256 < KK) {
            s1v = states[b * KK + tid + 256];
            d1  = durs[b * KK + tid + 256];
        }
        int v0 = d0, v1 = d1;
        #pragma unroll
        for (int off = 1; off < 64; off <<= 1) {
            int u0 = __shfl_up(v0, off, 64);
            int u1 = __shfl_up(v1, off, 64);
            if (lane >= off) { v0 += u0; v1 += u1; }
        }
        if (lane == 63) { csum[w] = v0; csum[4 + w] = v1; }
        __syncthreads();
        int off0 = 0, off1 = 0;
        #pragma unroll
        for (int c = 0; c < 8; ++c) {
            int cs = csum[c];
            off0 += (c < w) ? cs : 0;
            off1 += (c < 4 + w) ? cs : 0;
        }
        const int c0 = v0 + off0;      // cum[tid]
        const int c1 = v1 + off1;      // cum[tid+256]

        // interval-expand: thread k writes its segment's frames in this chunk.
        // segment k covers [cum[k]-dur[k], cum[k]); k==KK-1 extends to +inf (clip).
        {
            int a = c0 - d0, e = c0;
            a = (a < t0) ? t0 : a;
            e = (e > t0 + CHUNK) ? t0 + CHUNK : e;
            for (int t = a; t < e; ++t) fsl[t - t0] = s0v;
            int a1 = c1 - d1, e1 = (tid + 256 == KK - 1) ? t0 + CHUNK : c1;
            a1 = (a1 < t0) ? t0 : a1;
            e1 = (e1 > t0 + CHUNK) ? t0 + CHUNK : e1;
            for (int t = a1; t < e1; ++t) fsl[t - t0] = s1v;
        }
        __syncthreads();

        const int row = tid >> 5;          // 8 frames per iter
        const int d = (tid & 31) * 4;
        float acc = 0.f;
        if (t0 + CHUNK <= TT) {
            #pragma unroll
            for (int i = 0; i < CHUNK / 8; ++i) {
                const int t = t0 + i * 8 + row;
                const int s = fsl[i * 8 + row];
                const float4 o  = *(const float4*)(obs + ((size_t)(b * TT + t)) * OD + d);
                const float4 m  = *(const float4*)(mu  + (size_t)s * OD + d);
                const float4 lv = *(const float4*)(lvar + (size_t)s * OD + d);
                const float dx = o.x - m.x, dy = o.y - m.y, dz = o.z - m.z, dw = o.w - m.w;
                acc += lv.x + lv.y + lv.z + lv.w + 4.f * LOG2PI_F
                     + dx * dx * __expf(-lv.x) + dy * dy * __expf(-lv.y)
                     + dz * dz * __expf(-lv.z) + dw * dw * __expf(-lv.w);
            }
        } else {
            #pragma unroll
            for (int i = 0; i < CHUNK / 8; ++i) {
                const int t = t0 + i * 8 + row;
                if (t < TT) {
                    const int s = fsl[i * 8 + row];
                    const float4 o  = *(const float4*)(obs + ((size_t)(b * TT + t)) * OD + d);
                    const float4 m  = *(const float4*)(mu  + (size_t)s * OD + d);
                    const float4 lv = *(const float4*)(lvar + (size_t)s * OD + d);
                    const float dx = o.x - m.x, dy = o.y - m.y, dz = o.z - m.z, dw = o.w - m.w;
                    acc += lv.x + lv.y + lv.z + lv.w + 4.f * LOG2PI_F
                         + dx * dx * __expf(-lv.x) + dy * dy * __expf(-lv.y)
                         + dz * dz * __expf(-lv.z) + dw * dw * __expf(-lv.w);
                }
            }
        }
        for (int off = 32; off; off >>= 1) acc += __shfl_down(acc, off, 64);
        if ((tid & 63) == 0) red[tid >> 6] = acc;
        __syncthreads();
        if (tid == 0)
            ws[PART_OFF + bid] = -0.5f * (red[0] + red[1] + red[2] + red[3]);
    } else if (bid < BB * NCH + NS + 1) {
        // ---- LSE: transition row r<512, or initial logits (r==512) ----
        const int r = bid - BB * NCH;
        const float* src = (r < NS) ? (trans + (size_t)r * NS) : init_logits;
        float x0 = src[tid];
        float x1 = src[tid + 256];
        float m = fmaxf(x0, x1);
        for (int off = 32; off; off >>= 1) m = fmaxf(m, __shfl_down(m, off, 64));
        if ((tid & 63) == 0) red[tid >> 6] = m;
        __syncthreads();
        m = fmaxf(fmaxf(red[0], red[1]), fmaxf(red[2], red[3]));
        __syncthreads();
        float e = __expf(x0 - m) + __expf(x1 - m);
        for (int off = 32; off; off >>= 1) e += __shfl_down(e, off, 64);
        if ((tid & 63) == 0) red[tid >> 6] = e;
        __syncthreads();
        if (tid == 0)
            ws[(r < NS) ? r : 512] = m + __logf(red[0] + red[1] + red[2] + red[3]);
    } else {
        // ---- seq: duration terms + transition numerators + init logit ----
        const int b = bid - (BB * NCH + NS + 1);
        float lp = 0.f;
        for (int k = tid; k < KK; k += 256) {
            const int s = states[b * KK + k];
            const float dv = (float)durs[b * KK + k];
            const float a  = softplusf(alpha_p[s]) + 1e-6f;
            const float bt = softplusf(beta_p[s]) + 1e-6f;
            float v = (a - 1.f) * __logf(dv + 1e-8f) - bt * dv
                    + a * __logf(bt) - lgammaf(a);
            lp += (dv >= 1.f) ? v : -INFINITY;
            if (k < KK - 1)
                lp += trans[(size_t)s * NS + states[b * KK + k + 1]];
        }
        for (int off = 32; off; off >>= 1) lp += __shfl_down(lp, off, 64);
        if ((tid & 63) == 0) red[tid >> 6] = lp;
        __syncthreads();
        if (tid == 0)
            ws[SEQ_OFF + b] = red[0] + red[1] + red[2] + red[3]
                            + init_logits[states[b * KK]];
    }
}

__global__ __launch_bounds__(256) void fin_kernel(
    const int* __restrict__ states, const float* __restrict__ ws,
    float* __restrict__ out)
{
    const int b = blockIdx.x;
    const int tid = threadIdx.x;
    __shared__ float red[4];

    float lp = 0.f;
    if (tid < NCH)       lp = ws[PART_OFF + b * NCH + tid];
    else if (tid == NCH) lp = ws[SEQ_OFF + b] - ws[512];
    // subtract row_lse for each transition (2 KB table, L1-hot)
    for (int k = tid; k < KK - 1; k += 256)
        lp -= ws[states[b * KK + k]];
    for (int off = 32; off; off >>= 1) lp += __shfl_down(lp, off, 64);
    if ((tid & 63) == 0) red[tid >> 6] = lp;
    __syncthreads();
    if (tid == 0)
        out[b] = red[0] + red[1] + red[2] + red[3];
}

extern "C" void kernel_launch(void* const* d_in, const int* in_sizes, int n_in,
                              void* d_out, int out_size, void* d_ws, size_t ws_size,
                              hipStream_t stream) {
    const float* observations = (const float*)d_in[0];
    const float* alpha_p      = (const float*)d_in[1];
    const float* beta_p       = (const float*)d_in[2];
    const float* trans        = (const float*)d_in[3];
    const float* init_logits  = (const float*)d_in[4];
    const float* obs_means    = (const float*)d_in[5];
    const float* obs_logvars  = (const float*)d_in[6];
    const int*   state_seq    = (const int*)d_in[7];
    const int*   dur_seq      = (const int*)d_in[8];

    float* ws = (float*)d_ws;
    float* out = (float*)d_out;

    big_kernel<<<BB * NCH + NS + 1 + BB, 256, 0, stream>>>(
        observations, obs_means, obs_logvars, trans, init_logits,
        alpha_p, beta_p, state_seq, dur_seq, ws);
    fin_kernel<<<BB, 256, 0, stream>>>(state_seq, ws, out);
}